// Round 1
// baseline (11.546 us; speedup 1.0000x reference)
//
#include <hip/hip_runtime.h>

#define NQ    12
#define BATCH 1024

typedef float v2 __attribute__((ext_vector_type(2)));
typedef float v4 __attribute__((ext_vector_type(4)));

// tangent-form packed RY on v2-index bit P: pairs (m, m|2^P)
template<int P>
__device__ __forceinline__ void ryp_t8(v2 A[8], float t) {
#pragma unroll
    for (int m = 0; m < 8; ++m) {
        if ((m & (1 << P)) == 0) {
            const int j = m | (1 << P);
            const v2 Ai = A[m], Aj = A[j];
            A[m] = Ai - t * Aj;      // 1 pk_fma
            A[j] = Aj + t * Ai;      // 1 pk_fma
        }
    }
}

// tangent-form RY on the within-v2 bit: e' = e - t*o, o' = o + t*e
__device__ __forceinline__ void ry0_t8(v2 A[8], float t) {
    const v2 tv = v2{-t, t};
#pragma unroll
    for (int m = 0; m < 8; ++m) {
        const v2 sw = v2{A[m].y, A[m].x};
        A[m] = A[m] + tv * sw;
    }
}

__device__ __forceinline__ float rdlane(float v, int lane) {
    return __uint_as_float(__builtin_amdgcn_readlane(__float_as_uint(v), lane));
}

__global__ __launch_bounds__(256, 4)
void qc_kernel(const float* __restrict__ x, const float* __restrict__ th,
               float* __restrict__ out) {
    // col-major transpose buffer: addr = (w*16 + col)*68 + row
    //   col (16) = y0..y3, row (64) = y4..y9, stride 68 = 64+4 pad (16B-aligned, 2-way banks = free)
    __shared__ float buf1[4 * 16 * 68];
    __shared__ float obuf[12 * 4];

    const int b = blockIdx.x;             // one batch element per block (4 waves)
    const int w = threadIdx.x >> 6;       // wave bits: w0 = qubit 10, w1 = qubit 11
    const int l = threadIdx.x & 63;
    const int w0 = w & 1, w1 = w >> 1;
    const float* xb = x + b * NQ;

    // ---- lane-parallel sincos (identical to verified 2-wave version) ----
    const int q_ = l & 31;
    float ang;
    if (l & 32) ang = (q_ < 12) ? 0.5f * th[NQ + q_] : 0.0f;
    else        { const int m_ = (q_ < 12) ? q_ : 11; ang = 0.5f * (xb[m_] + th[m_]); }
    float sv_, cv_;
    __sincosf(ang, &sv_, &cv_);
    const float tl = __fdividef(sv_, cv_);

    float pt = cv_;
    pt *= __shfl_xor(pt, 1, 64);
    pt *= __shfl_xor(pt, 2, 64);
    pt *= __shfl_xor(pt, 4, 64);
    pt *= __shfl_xor(pt, 8, 64);
    const float C = rdlane(pt, 32);       // prod cos(th1_q/2), deferred

    float c_[NQ], s_[NQ], t1[NQ];
#pragma unroll
    for (int q = 0; q < NQ; ++q) {
        c_[q] = rdlane(cv_, q);
        s_[q] = rdlane(sv_, q);
        t1[q] = rdlane(tl, 32 + q);
    }

    // ---- POST-ring#1 product state, layout L1: ----
    // t0..t3 = reg bits (v2 bit + 3 m bits) = y0..y3; l0..l5 = y4..y9; w0 = y10, w1 = y11
    // pre-ring factors: u_q = y_q^y_{q-1} (q>=2), u1 = y0^y1^y11, u0 = y0^y11
    const int l0=l&1, l1=(l>>1)&1, l2=(l>>2)&1, l3=(l>>3)&1, l4=(l>>4)&1, l5=(l>>5)&1;
    float GL = ((l1^l0) ? s_[5] : c_[5]) * ((l2^l1) ? s_[6] : c_[6]);
    GL *= ((l3^l2) ? s_[7] : c_[7]) * ((l4^l3) ? s_[8] : c_[8]);
    GL *= ((l5^l4) ? s_[9] : c_[9]) * ((w0^l5) ? s_[10] : c_[10]);
    GL *= ((w0^w1) ? s_[11] : c_[11]) * C;
    const float GL0 = GL * (l0 ? s_[4] : c_[4]);    // t3=0: u4 = l0
    const float GL1 = GL * (l0 ? c_[4] : s_[4]);    // t3=1: u4 = l0^1

    const float f0_0 = w1 ? s_[0] : c_[0], f0_1 = w1 ? c_[0] : s_[0];   // u0 = t0^w1
    const float f1_0 = w1 ? s_[1] : c_[1], f1_1 = w1 ? c_[1] : s_[1];   // u1 = (t0^t1)^w1

    v2 A[8];
    A[0] = v2{f0_0 * f1_0, f0_1 * f1_1};
    A[1] = v2{f0_0 * f1_1, f0_1 * f1_0};
#pragma unroll
    for (int k = 2; k < 4; ++k) {
#pragma unroll
        for (int m = 0; m < (1 << (k - 1)); ++m) {
            const int bp = (m >> (k - 2)) & 1;      // t_{k-1}
            A[m | (1 << (k - 1))] = A[m] * (bp ? c_[k] : s_[k]);
            A[m]                  = A[m] * (bp ? s_[k] : c_[k]);
        }
    }
#pragma unroll
    for (int m = 0; m < 8; ++m) A[m] *= (m & 4) ? GL1 : GL0;

    // ---- layer-1 phase 1: qubits 0..3 on reg bits (tangent form) ----
    ry0_t8(A, t1[0]);
    ryp_t8<0>(A, t1[1]);
    ryp_t8<1>(A, t1[2]);
    ryp_t8<2>(A, t1[3]);

    // ---- transpose write (col-major): col = 2m+c (y0..y3), row = l (y4..y9) ----
    {
        float* wp = &buf1[w * 1088 + l];
#pragma unroll
        for (int m = 0; m < 8; ++m) {
            wp[(2*m)   * 68] = A[m].x;
            wp[(2*m+1) * 68] = A[m].y;
        }
    }
    __syncthreads();

    // ---- transpose read (16 x ds_read_b128) + fold tangent-RY(q10=w0, q11=w1) ----
    // new = (own + s0*t10*P(w0)) + s1*t11*(P(w1) + s0*t10*P(w0,w1)); signs: bit ? +t : -t
    {
        const float st0 = w0 ? t1[10] : -t1[10];
        const float st1 = w1 ? t1[11] : -t1[11];
        const int rbase = (l & 15) * 68 + (l & 48);
        const float* r00 = &buf1[ w      * 1088 + rbase];   // own
        const float* r01 = &buf1[(w ^ 1) * 1088 + rbase];   // flip w0 (q10 partner)
        const float* r10 = &buf1[(w ^ 2) * 1088 + rbase];   // flip w1 (q11 partner)
        const float* r11 = &buf1[(w ^ 3) * 1088 + rbase];   // flip both
#pragma unroll
        for (int k = 0; k < 4; ++k) {
            const v4 a  = *reinterpret_cast<const v4*>(r00 + 4*k);
            const v4 bq = *reinterpret_cast<const v4*>(r01 + 4*k);
            const v4 cq = *reinterpret_cast<const v4*>(r10 + 4*k);
            const v4 dq = *reinterpret_cast<const v4*>(r11 + 4*k);
            const v4 u = a  + st0 * bq;
            const v4 v = cq + st0 * dq;
            const v4 r = u + st1 * v;
            A[2*k]   = v2{r.x, r.y};
            A[2*k+1] = v2{r.z, r.w};
        }
    }
    // layout L2: reg = qubits 4..7 (t0=z4, m=z5..z7), l0..l3 = z0..z3,
    //            l4 = z8, l5 = z9, w0 = z10, w1 = z11 (q10,q11 gates applied)

    // ---- layer-1 phase 2: qubits 4..7 on reg bits ----
    ry0_t8(A, t1[4]);
    ryp_t8<0>(A, t1[5]);
    ryp_t8<1>(A, t1[6]);
    ryp_t8<2>(A, t1[7]);

    // qubit 8 = lane bit 4
    {
        const float tt = (l & 16) ? t1[8] : -t1[8];
#pragma unroll
        for (int m = 0; m < 8; ++m) {
            const v2 p = v2{__shfl_xor(A[m].x, 16, 64), __shfl_xor(A[m].y, 16, 64)};
            A[m] = A[m] + tt * p;
        }
    }
    // qubit 9 = lane bit 5
    {
        const float tt = (l & 32) ? t1[9] : -t1[9];
#pragma unroll
        for (int m = 0; m < 8; ++m) {
            const v2 p = v2{__shfl_xor(A[m].x, 32, 64), __shfl_xor(A[m].y, 32, 64)};
            A[m] = A[m] + tt * p;
        }
    }

    // ---- measurement (ring #2 absorbed): Z_q = E[(-1)^{z0^...^zq}], Z0 = E[(-1)^{z1^...^z11}] ----
#pragma unroll
    for (int m = 0; m < 8; ++m) A[m] *= A[m];

    float S = 0.f, d0[8];
#pragma unroll
    for (int m = 0; m < 8; ++m) { S += A[m].x + A[m].y; d0[m] = A[m].x - A[m].y; }
    float V1 = 0.f;                                   // sign z4
#pragma unroll
    for (int i = 0; i < 8; ++i) V1 += d0[i];
    float d1[4];
#pragma unroll
    for (int i = 0; i < 4; ++i) d1[i] = d0[2*i] - d0[2*i+1];
    const float V2 = d1[0] + d1[1] + d1[2] + d1[3];   // sign z4^z5
    const float d2a = d1[0] - d1[1], d2b = d1[2] - d1[3];
    const float V3 = d2a + d2b;                       // sign z4^z5^z6
    const float V4 = d2a - d2b;                       // sign z4^z5^z6^z7

    // Z4..Z7: packed 4-value butterfly (lane-mask 15 sign applied first)
    const int pl = __popc(l & 15) & 1;
    float y0 = pl ? -V1 : V1;
    float y1 = pl ? -V2 : V2;
    float y2 = pl ? -V3 : V3;
    float y3 = pl ? -V4 : V4;
    y0 += __shfl_xor(y0, 1, 64); y1 += __shfl_xor(y1, 1, 64);
    y2 += __shfl_xor(y2, 1, 64); y3 += __shfl_xor(y3, 1, 64);
    y0 += __shfl_xor(y0, 2, 64); y1 += __shfl_xor(y1, 2, 64);
    y2 += __shfl_xor(y2, 2, 64); y3 += __shfl_xor(y3, 2, 64);
    const int g = l & 3;
    float y = (g == 0) ? y0 : (g == 1) ? y1 : (g == 2) ? y2 : y3;
    y += __shfl_xor(y,  4, 64);
    y += __shfl_xor(y,  8, 64);
    y += __shfl_xor(y, 16, 64);
    y += __shfl_xor(y, 32, 64);
    if (l < 4) obuf[(4 + l) * 4 + w] = y;             // q4..q7, all-wave plus

    // WHT of S (Z1@3, Z2@7, Z3@15) and V4 (Z8@31, Z9/Z10/Z11@63, Z0@62)
    float wS = S, wV = V4;
#pragma unroll
    for (int k = 0; k < 6; ++k) {
        float pS = __shfl_xor(wS, 1 << k, 64);
        wS = ((l >> k) & 1) ? (pS - wS) : (wS + pS);
        float pV = __shfl_xor(wV, 1 << k, 64);
        wV = ((l >> k) & 1) ? (pV - wV) : (wV + pV);
    }

    if (l == 3)  obuf[1 * 4 + w] = wS;
    if (l == 7)  obuf[2 * 4 + w] = wS;
    if (l == 15) obuf[3 * 4 + w] = wS;
    if (l == 31) obuf[8 * 4 + w] = wV;
    if (l == 62) obuf[0 * 4 + w] = wV;                // Z0 pre wave-sign
    if (l == 63) obuf[9 * 4 + w] = wV;                // Z9 (Z10/Z11 via wave signs)
    __syncthreads();

    if (threadIdx.x < NQ) {
        const int q = threadIdx.x;
        const int src = (q >= 10) ? 9 : q;
        const float p0 = obuf[src * 4 + 0], p1 = obuf[src * 4 + 1];
        const float p2 = obuf[src * 4 + 2], p3 = obuf[src * 4 + 3];
        float r;
        if (q == 0 || q == 11) r = p0 - p1 - p2 + p3;   // sign (-1)^(z10^z11)
        else if (q == 10)      r = p0 - p1 + p2 - p3;   // sign (-1)^z10
        else                   r = p0 + p1 + p2 + p3;
        out[b * NQ + q] = r;
    }
}

extern "C" void kernel_launch(void* const* d_in, const int* in_sizes, int n_in,
                              void* d_out, int out_size, void* d_ws, size_t ws_size,
                              hipStream_t stream) {
    const float* x  = (const float*)d_in[0];   // (1024, 12) f32
    const float* th = (const float*)d_in[1];   // (2, 12)    f32
    float* out = (float*)d_out;                // (1024, 12) f32
    (void)in_sizes; (void)n_in; (void)out_size; (void)d_ws; (void)ws_size;

    qc_kernel<<<BATCH, 256, 0, stream>>>(x, th, out);   // 4 waves per batch element
}

// Round 2
// 9.870 us; speedup vs baseline: 1.1698x; 1.1698x over previous
//
#include <hip/hip_runtime.h>

#define NQ    12
#define BATCH 1024

typedef float v2 __attribute__((ext_vector_type(2)));
typedef float v4 __attribute__((ext_vector_type(4)));

// tangent-form packed RY on v2-index bit P: A' = [[1,-t],[t,1]] applied to (m, m|2^P)
template<int P>
__device__ __forceinline__ void ryp_t(v2 A[16], float t) {
#pragma unroll
    for (int m = 0; m < 16; ++m) {
        if ((m & (1 << P)) == 0) {
            const int j = m | (1 << P);
            const v2 Ai = A[m], Aj = A[j];
            A[m] = Ai - t * Aj;      // 1 pk_fma
            A[j] = Aj + t * Ai;      // 1 pk_fma
        }
    }
}

// tangent-form RY on the within-v2 bit: e' = e - t*o, o' = o + t*e (1 pk_fma via .yx)
__device__ __forceinline__ void ry0_t(v2 A[16], float t) {
    const v2 tv = v2{-t, t};
#pragma unroll
    for (int m = 0; m < 16; ++m) {
        const v2 sw = v2{A[m].y, A[m].x};
        A[m] = A[m] + tv * sw;
    }
}

__device__ __forceinline__ float rdlane(float v, int lane) {
    return __uint_as_float(__builtin_amdgcn_readlane(__float_as_uint(v), lane));
}

__global__ __launch_bounds__(128, 2)
void qc_kernel(const float* __restrict__ x, const float* __restrict__ th,
               float* __restrict__ out) {
    // col-major transpose buffer: addr = w*2176 + col*68 + row
    //   col (32) = qubits 0..4 (old reg index), row (64) = old lane (qubits 5..10)
    //   stride 68 = 64+4: keeps 16B alignment; read pattern covers all 32 banks evenly
    __shared__ __attribute__((aligned(16))) float buf1[2 * 32 * 68];
    __shared__ float obuf[12 * 2];

    const int b = blockIdx.x;             // one batch element per block (2 waves)
    const int w = threadIdx.x >> 6;       // wave bit = qubit 11
    const int l = threadIdx.x & 63;
    const float* xb = x + b * NQ;

    // ---- lane-parallel sincos (verified R0) ----
    const int q_ = l & 31;
    float ang;
    if (l & 32) ang = (q_ < 12) ? 0.5f * th[NQ + q_] : 0.0f;
    else        { const int m_ = (q_ < 12) ? q_ : 11; ang = 0.5f * (xb[m_] + th[m_]); }
    float sv_, cv_;
    __sincosf(ang, &sv_, &cv_);
    const float tl = __fdividef(sv_, cv_);   // tan(ang); valid where used (lanes 32..43)

    // C = prod_{q=0..11} cos(th1_q/2): product tree over lanes 32..47
    float pt = cv_;
    pt *= __shfl_xor(pt, 1, 64);
    pt *= __shfl_xor(pt, 2, 64);
    pt *= __shfl_xor(pt, 4, 64);
    pt *= __shfl_xor(pt, 8, 64);
    const float C = rdlane(pt, 32);

    float c_[NQ], s_[NQ], t1[NQ];
#pragma unroll
    for (int q = 0; q < NQ; ++q) {
        c_[q] = rdlane(cv_, q);
        s_[q] = rdlane(sv_, q);
        t1[q] = rdlane(tl, 32 + q);
    }

    // ---- build POST-ring#1 state, layout L1 (verified R0): ----
    // t0..t4 = reg bits (qubits 0..4), l0..l5 = lane bits (qubits 5..10), wave = qubit 11
    const int l0=l&1, l1=(l>>1)&1, l2=(l>>2)&1, l3=(l>>3)&1, l4=(l>>4)&1, l5=(l>>5)&1;
    float GL = ((l1^l0) ? s_[6] : c_[6]) * ((l2^l1) ? s_[7] : c_[7]);
    GL *= ((l3^l2) ? s_[8] : c_[8]) * ((l4^l3) ? s_[9] : c_[9]);
    GL *= ((l5^l4) ? s_[10] : c_[10]) * ((w^l5) ? s_[11] : c_[11]);
    GL *= C;                                        // deferred layer-1 cosine product
    const float GL0 = GL * (l0 ? s_[5] : c_[5]);    // regs with r4=0  (b5 = l0)
    const float GL1 = GL * (l0 ? c_[5] : s_[5]);    // regs with r4=1  (b5 = l0^1)

    const float f0_0 = w ? s_[0] : c_[0], f0_1 = w ? c_[0] : s_[0];   // g0(r0^w)
    const float f1_0 = w ? s_[1] : c_[1], f1_1 = w ? c_[1] : s_[1];   // g1(u^w)

    v2 A[16];
    A[0] = v2{f0_0 * f1_0, f0_1 * f1_1};
    A[1] = v2{f0_0 * f1_1, f0_1 * f1_0};
#pragma unroll
    for (int k = 2; k < 5; ++k) {
#pragma unroll
        for (int m = 0; m < (1 << (k - 1)); ++m) {
            const int bp = (m >> (k - 2)) & 1;
            A[m | (1 << (k - 1))] = A[m] * (bp ? c_[k] : s_[k]);
            A[m]                  = A[m] * (bp ? s_[k] : c_[k]);
        }
    }
#pragma unroll
    for (int m = 0; m < 16; ++m) A[m] *= (m & 8) ? GL1 : GL0;

    // ---- layer-1 phase 1: qubits 0..4 on reg bits (tangent form) ----
    ry0_t(A, t1[0]);
    ryp_t<0>(A, t1[1]);
    ryp_t<1>(A, t1[2]);
    ryp_t<2>(A, t1[3]);
    ryp_t<3>(A, t1[4]);

    // ---- transpose write (col-major): col = 2m+c (qubits 0..4), row = l ----
    {
        float* wp = &buf1[w * 2176 + l];
#pragma unroll
        for (int m = 0; m < 16; ++m) {
            wp[(2*m)   * 68] = A[m].x;
            wp[(2*m+1) * 68] = A[m].y;
        }
    }
    __syncthreads();

    // ---- transpose read (32 x ds_read_b128) + fold tangent-RY(q10) AND RY(q11) ----
    // q10 = old row bit 5 (row^32 partner), q11 = other wave's buffer half.
    // new = (own + s10*flip10) + s11*(flip11 + s10*flip_both); sign: bit ? +t : -t
    // (RY gates on distinct qubits commute, so applying q10/q11 before q5..q9 is exact.)
    {
        const float s10 = (l & 32) ? t1[10] : -t1[10];
        const float s11 = w ? t1[11] : -t1[11];
        const int basec = (l & 31) * 68;
        const int ro = (l & 32);            // own-q10 row offset (new q10 = l5)
        const int rf = ro ^ 32;
        const float* p00 = &buf1[ w      * 2176 + basec + ro];   // own q10, own q11
        const float* p01 = &buf1[ w      * 2176 + basec + rf];   // flip q10
        const float* p10 = &buf1[(w ^ 1) * 2176 + basec + ro];   // flip q11
        const float* p11 = &buf1[(w ^ 1) * 2176 + basec + rf];   // flip both
#pragma unroll
        for (int k = 0; k < 8; ++k) {
            const v4 a  = *reinterpret_cast<const v4*>(p00 + 4*k);
            const v4 bq = *reinterpret_cast<const v4*>(p01 + 4*k);
            const v4 cq = *reinterpret_cast<const v4*>(p10 + 4*k);
            const v4 dq = *reinterpret_cast<const v4*>(p11 + 4*k);
            const v4 u = a  + s10 * bq;
            const v4 v = cq + s10 * dq;
            const v4 r = u + s11 * v;
            A[2*k]   = v2{r.x, r.y};
            A[2*k+1] = v2{r.z, r.w};
        }
    }
    // layout L2: reg bits = qubits 5..9, lane bits 0-4 = qubits 0..4,
    //            lane bit 5 = qubit 10, wave = qubit 11 (q10 & q11 gates applied)

    // ---- layer-1 phase 2: qubits 5..9 on reg bits (tangent form) ----
    ry0_t(A, t1[5]);
    ryp_t<0>(A, t1[6]);
    ryp_t<1>(A, t1[7]);
    ryp_t<2>(A, t1[8]);
    ryp_t<3>(A, t1[9]);

    // ---- measurement (ring #2 absorbed; L2 mapping; verified R0) ----
#pragma unroll
    for (int m = 0; m < 16; ++m) A[m] *= A[m];

    float S = 0.f;
#pragma unroll
    for (int m = 0; m < 16; ++m) S += A[m].x + A[m].y;
    float d0[16];
#pragma unroll
    for (int m = 0; m < 16; ++m) d0[m] = A[m].x - A[m].y;
    float P1 = 0.f;
#pragma unroll
    for (int i = 0; i < 16; ++i) P1 += d0[i];
    float d1[8];
#pragma unroll
    for (int i = 0; i < 8; ++i) d1[i] = d0[2*i] - d0[2*i+1];
    float P3 = 0.f;
#pragma unroll
    for (int i = 0; i < 8; ++i) P3 += d1[i];
    float d2[4];
#pragma unroll
    for (int i = 0; i < 4; ++i) d2[i] = d1[2*i] - d1[2*i+1];
    const float P7  = d2[0] + d2[1] + d2[2] + d2[3];
    const float d3a = d2[0] - d2[1], d3b = d2[2] - d2[3];
    const float PF  = d3a + d3b;
    const float PV  = d3a - d3b;

    // Z5..Z8: packed 4-value butterfly (lane-mask 0x1F sign applied first)
    const int pl5 = __popc(l & 31) & 1;
    float y0 = pl5 ? -P1 : P1;
    float y1 = pl5 ? -P3 : P3;
    float y2 = pl5 ? -P7 : P7;
    float y3 = pl5 ? -PF : PF;
    y0 += __shfl_xor(y0, 1, 64); y1 += __shfl_xor(y1, 1, 64);
    y2 += __shfl_xor(y2, 1, 64); y3 += __shfl_xor(y3, 1, 64);
    y0 += __shfl_xor(y0, 2, 64); y1 += __shfl_xor(y1, 2, 64);
    y2 += __shfl_xor(y2, 2, 64); y3 += __shfl_xor(y3, 2, 64);
    const int g = l & 3;
    float y = (g == 0) ? y0 : (g == 1) ? y1 : (g == 2) ? y2 : y3;
    y += __shfl_xor(y,  4, 64);
    y += __shfl_xor(y,  8, 64);
    y += __shfl_xor(y, 16, 64);
    y += __shfl_xor(y, 32, 64);
    if (l < 4) obuf[(5 + l) * 2 + w] = y;   // lane l holds full sum of value l&3

    // WHT of S (Z1..Z4 at lanes 3,7,15,31) and PV (Z0@62, Z9@31, Z10/Z11@63)
    float wS = S, wV = PV;
#pragma unroll
    for (int k = 0; k < 6; ++k) {
        float pS = __shfl_xor(wS, 1 << k, 64);
        wS = ((l >> k) & 1) ? (pS - wS) : (wS + pS);
        float pV = __shfl_xor(wV, 1 << k, 64);
        wV = ((l >> k) & 1) ? (pV - wV) : (wV + pV);
    }

    if (l == 3)  obuf[1*2 + w]  = wS;
    if (l == 7)  obuf[2*2 + w]  = wS;
    if (l == 15) obuf[3*2 + w]  = wS;
    if (l == 31) { obuf[4*2 + w] = wS; obuf[9*2 + w] = wV; }
    if (l == 62) obuf[0*2 + w]  = wV;
    if (l == 63) { obuf[10*2 + w] = wV; obuf[11*2 + w] = wV; }
    __syncthreads();

    if (threadIdx.x < NQ) {
        const int q = threadIdx.x;
        const float p0 = obuf[q*2 + 0], p1 = obuf[q*2 + 1];
        out[b * NQ + q] = (q == 0 || q == 11) ? (p0 - p1) : (p0 + p1);
    }
}

extern "C" void kernel_launch(void* const* d_in, const int* in_sizes, int n_in,
                              void* d_out, int out_size, void* d_ws, size_t ws_size,
                              hipStream_t stream) {
    const float* x  = (const float*)d_in[0];   // (1024, 12) f32
    const float* th = (const float*)d_in[1];   // (2, 12)    f32
    float* out = (float*)d_out;                // (1024, 12) f32
    (void)in_sizes; (void)n_in; (void)out_size; (void)d_ws; (void)ws_size;

    qc_kernel<<<BATCH, 128, 0, stream>>>(x, th, out);   // 2 waves per batch element
}

// Round 3
// 9.682 us; speedup vs baseline: 1.1925x; 1.0194x over previous
//
#include <hip/hip_runtime.h>

#define NQ    12
#define BATCH 1024

typedef float v2 __attribute__((ext_vector_type(2)));
typedef float v4 __attribute__((ext_vector_type(4)));

// tangent-form packed RY on v2-index bit P: A' = [[1,-t],[t,1]] applied to (m, m|2^P)
template<int P>
__device__ __forceinline__ void ryp_t(v2 A[16], float t) {
#pragma unroll
    for (int m = 0; m < 16; ++m) {
        if ((m & (1 << P)) == 0) {
            const int j = m | (1 << P);
            const v2 Ai = A[m], Aj = A[j];
            A[m] = Ai - t * Aj;      // 1 pk_fma
            A[j] = Aj + t * Ai;      // 1 pk_fma
        }
    }
}

// tangent-form RY on the within-v2 bit: e' = e - t*o, o' = o + t*e (1 pk_fma via .yx)
__device__ __forceinline__ void ry0_t(v2 A[16], float t) {
    const v2 tv = v2{-t, t};
#pragma unroll
    for (int m = 0; m < 16; ++m) {
        const v2 sw = v2{A[m].y, A[m].x};
        A[m] = A[m] + tv * sw;
    }
}

__device__ __forceinline__ float rdlane(float v, int lane) {
    return __uint_as_float(__builtin_amdgcn_readlane(__float_as_uint(v), lane));
}

// DPP quad_perm cross-lane (VALU pipe): 0xB1 = xor1 [1,0,3,2], 0x4E = xor2 [2,3,0,1]
template<int CTRL>
__device__ __forceinline__ float dppx(float v) {
    return __int_as_float(__builtin_amdgcn_mov_dpp(__float_as_int(v), CTRL, 0xF, 0xF, true));
}
// ds_swizzle BitMode: offset = (xor<<10) | 0x1F  (xor within 32-lane group)
template<int PAT>
__device__ __forceinline__ float swz(float v) {
    return __int_as_float(__builtin_amdgcn_ds_swizzle(__float_as_int(v), PAT));
}

__global__ __launch_bounds__(512, 2)
void qc_kernel(const float* __restrict__ x, const float* __restrict__ th,
               float* __restrict__ out) {
    // 4 independent batch elements (wave-pairs) per block; per pair:
    // col-major transpose buffer: addr = w*2176 + col*68 + row  (stride 68 = 64+4 pad)
    __shared__ __attribute__((aligned(16))) float buf1[4 * 4352];
    __shared__ float obuf[4 * 24];

    const int tid = threadIdx.x;
    const int p = tid >> 7;               // wave-pair (batch sub-element) 0..3
    const int w = (tid >> 6) & 1;         // wave bit within pair = qubit 11
    const int l = tid & 63;
    const int b = blockIdx.x * 4 + p;
    const float* xb = x + b * NQ;
    float* bufp  = &buf1[p * 4352];
    float* obufp = &obuf[p * 24];

    // ---- lane-parallel sincos (verified R0) ----
    const int q_ = l & 31;
    float ang;
    if (l & 32) ang = (q_ < 12) ? 0.5f * th[NQ + q_] : 0.0f;
    else        { const int m_ = (q_ < 12) ? q_ : 11; ang = 0.5f * (xb[m_] + th[m_]); }
    float sv_, cv_;
    __sincosf(ang, &sv_, &cv_);
    const float tl = __fdividef(sv_, cv_);   // tan(ang); valid where used (lanes 32..43)

    // C = prod_{q=0..11} cos(th1_q/2): product tree over lanes 32..47 (DPP + swizzle)
    float pt = cv_;
    pt *= dppx<0xB1>(pt);        // xor 1
    pt *= dppx<0x4E>(pt);        // xor 2
    pt *= swz<0x101F>(pt);       // xor 4
    pt *= swz<0x201F>(pt);       // xor 8
    const float C = rdlane(pt, 32);

    float c_[NQ], s_[NQ], t1[NQ];
#pragma unroll
    for (int q = 0; q < NQ; ++q) {
        c_[q] = rdlane(cv_, q);
        s_[q] = rdlane(sv_, q);
        t1[q] = rdlane(tl, 32 + q);
    }

    // ---- build POST-ring#1 state, layout L1 (verified R0): ----
    // t0..t4 = reg bits (qubits 0..4), l0..l5 = lane bits (qubits 5..10), wave = qubit 11
    const int l0=l&1, l1=(l>>1)&1, l2=(l>>2)&1, l3=(l>>3)&1, l4=(l>>4)&1, l5=(l>>5)&1;
    float GL = ((l1^l0) ? s_[6] : c_[6]) * ((l2^l1) ? s_[7] : c_[7]);
    GL *= ((l3^l2) ? s_[8] : c_[8]) * ((l4^l3) ? s_[9] : c_[9]);
    GL *= ((l5^l4) ? s_[10] : c_[10]) * ((w^l5) ? s_[11] : c_[11]);
    GL *= C;                                        // deferred layer-1 cosine product
    const float GL0 = GL * (l0 ? s_[5] : c_[5]);    // regs with r4=0  (b5 = l0)
    const float GL1 = GL * (l0 ? c_[5] : s_[5]);    // regs with r4=1  (b5 = l0^1)

    const float f0_0 = w ? s_[0] : c_[0], f0_1 = w ? c_[0] : s_[0];   // g0(r0^w)
    const float f1_0 = w ? s_[1] : c_[1], f1_1 = w ? c_[1] : s_[1];   // g1(u^w)

    v2 A[16];
    A[0] = v2{f0_0 * f1_0, f0_1 * f1_1};
    A[1] = v2{f0_0 * f1_1, f0_1 * f1_0};
#pragma unroll
    for (int k = 2; k < 5; ++k) {
#pragma unroll
        for (int m = 0; m < (1 << (k - 1)); ++m) {
            const int bp = (m >> (k - 2)) & 1;
            A[m | (1 << (k - 1))] = A[m] * (bp ? c_[k] : s_[k]);
            A[m]                  = A[m] * (bp ? s_[k] : c_[k]);
        }
    }
#pragma unroll
    for (int m = 0; m < 16; ++m) A[m] *= (m & 8) ? GL1 : GL0;

    // ---- layer-1 phase 1: qubits 0..4 on reg bits (tangent form) ----
    ry0_t(A, t1[0]);
    ryp_t<0>(A, t1[1]);
    ryp_t<1>(A, t1[2]);
    ryp_t<2>(A, t1[3]);
    ryp_t<3>(A, t1[4]);

    // ---- transpose write (col-major): col = 2m+c (qubits 0..4), row = l ----
    {
        float* wp = &bufp[w * 2176 + l];
#pragma unroll
        for (int m = 0; m < 16; ++m) {
            wp[(2*m)   * 68] = A[m].x;
            wp[(2*m+1) * 68] = A[m].y;
        }
    }
    __syncthreads();

    // ---- transpose read (32 x ds_read_b128) + fold tangent-RY(q10) AND RY(q11) ----
    // new = (own + s10*flip10) + s11*(flip11 + s10*flip_both); sign: bit ? +t : -t
    {
        const float s10 = (l & 32) ? t1[10] : -t1[10];
        const float s11 = w ? t1[11] : -t1[11];
        const int basec = (l & 31) * 68;
        const int ro = (l & 32);            // own-q10 row offset (new q10 = l5)
        const int rf = ro ^ 32;
        const float* p00 = &bufp[ w      * 2176 + basec + ro];   // own q10, own q11
        const float* p01 = &bufp[ w      * 2176 + basec + rf];   // flip q10
        const float* p10 = &bufp[(w ^ 1) * 2176 + basec + ro];   // flip q11
        const float* p11 = &bufp[(w ^ 1) * 2176 + basec + rf];   // flip both
#pragma unroll
        for (int k = 0; k < 8; ++k) {
            const v4 a  = *reinterpret_cast<const v4*>(p00 + 4*k);
            const v4 bq = *reinterpret_cast<const v4*>(p01 + 4*k);
            const v4 cq = *reinterpret_cast<const v4*>(p10 + 4*k);
            const v4 dq = *reinterpret_cast<const v4*>(p11 + 4*k);
            const v4 u = a  + s10 * bq;
            const v4 v = cq + s10 * dq;
            const v4 r = u + s11 * v;
            A[2*k]   = v2{r.x, r.y};
            A[2*k+1] = v2{r.z, r.w};
        }
    }
    // layout L2: reg bits = qubits 5..9, lane bits 0-4 = qubits 0..4,
    //            lane bit 5 = qubit 10, wave = qubit 11 (q10 & q11 gates applied)

    // ---- layer-1 phase 2: qubits 5..9 on reg bits (tangent form) ----
    ry0_t(A, t1[5]);
    ryp_t<0>(A, t1[6]);
    ryp_t<1>(A, t1[7]);
    ryp_t<2>(A, t1[8]);
    ryp_t<3>(A, t1[9]);

    // ---- measurement: packed pairwise tree (ring #2 absorbed; L2 mapping) ----
    // S = sum; P1 sign t0; P3 sign t0^t1; P7 t0^t1^t2; PF t0..t3; PV t0..t4
#pragma unroll
    for (int m = 0; m < 16; ++m) A[m] *= A[m];

    v2 e[8], f[8];
#pragma unroll
    for (int i = 0; i < 8; ++i) { e[i] = A[2*i] + A[2*i+1]; f[i] = A[2*i] - A[2*i+1]; }
    v2 se = ((e[0]+e[1]) + (e[2]+e[3])) + ((e[4]+e[5]) + (e[6]+e[7]));
    v2 sf = ((f[0]+f[1]) + (f[2]+f[3])) + ((f[4]+f[5]) + (f[6]+f[7]));
    v2 gq[4];
#pragma unroll
    for (int j = 0; j < 4; ++j) gq[j] = f[2*j] - f[2*j+1];
    const v2 sg2 = (gq[0]+gq[1]) + (gq[2]+gq[3]);
    const v2 h0 = gq[0] - gq[1], h1 = gq[2] - gq[3];
    const v2 sh = h0 + h1;
    const v2 iv = h0 - h1;
    const float S  = se.x + se.y;
    const float P1 = se.x - se.y;
    const float P3 = sf.x - sf.y;
    const float P7 = sg2.x - sg2.y;
    const float PF = sh.x - sh.y;
    const float PV = iv.x - iv.y;

    // Z5..Z8: packed 4-value butterfly (lane-mask 0x1F sign applied first)
    const int pl5 = __popc(l & 31) & 1;
    float y0 = pl5 ? -P1 : P1;
    float y1 = pl5 ? -P3 : P3;
    float y2 = pl5 ? -P7 : P7;
    float y3 = pl5 ? -PF : PF;
    y0 += dppx<0xB1>(y0); y1 += dppx<0xB1>(y1);
    y2 += dppx<0xB1>(y2); y3 += dppx<0xB1>(y3);
    y0 += dppx<0x4E>(y0); y1 += dppx<0x4E>(y1);
    y2 += dppx<0x4E>(y2); y3 += dppx<0x4E>(y3);
    const int g = l & 3;
    float y = (g == 0) ? y0 : (g == 1) ? y1 : (g == 2) ? y2 : y3;
    y += swz<0x101F>(y);          // xor 4
    y += swz<0x201F>(y);          // xor 8
    y += swz<0x401F>(y);          // xor 16
    y += __shfl_xor(y, 32, 64);   // xor 32
    if (l < 4) obufp[(5 + l) * 2 + w] = y;   // lane l holds full sum of value l&3

    // WHT of S (Z1..Z4 at lanes 3,7,15,31) and PV (Z0@62, Z9@31, Z10/Z11@63)
    // fma form: w' = fma(sign_k, w, partner), sign_k = bit_k ? -1 : +1
    const float sg0 = (l & 1)  ? -1.f : 1.f;
    const float sg1 = (l & 2)  ? -1.f : 1.f;
    const float sg2s = (l & 4) ? -1.f : 1.f;
    const float sg3 = (l & 8)  ? -1.f : 1.f;
    const float sg4 = (l & 16) ? -1.f : 1.f;
    const float sg5 = (l & 32) ? -1.f : 1.f;
    float wS = S, wV = PV;
    { const float pS = dppx<0xB1>(wS),  pV = dppx<0xB1>(wV);  wS = __builtin_fmaf(sg0, wS, pS); wV = __builtin_fmaf(sg0, wV, pV); }
    { const float pS = dppx<0x4E>(wS),  pV = dppx<0x4E>(wV);  wS = __builtin_fmaf(sg1, wS, pS); wV = __builtin_fmaf(sg1, wV, pV); }
    { const float pS = swz<0x101F>(wS), pV = swz<0x101F>(wV); wS = __builtin_fmaf(sg2s, wS, pS); wV = __builtin_fmaf(sg2s, wV, pV); }
    { const float pS = swz<0x201F>(wS), pV = swz<0x201F>(wV); wS = __builtin_fmaf(sg3, wS, pS); wV = __builtin_fmaf(sg3, wV, pV); }
    { const float pS = swz<0x401F>(wS), pV = swz<0x401F>(wV); wS = __builtin_fmaf(sg4, wS, pS); wV = __builtin_fmaf(sg4, wV, pV); }
    { const float pS = __shfl_xor(wS, 32, 64), pV = __shfl_xor(wV, 32, 64);
      wS = __builtin_fmaf(sg5, wS, pS); wV = __builtin_fmaf(sg5, wV, pV); }

    if (l == 3)  obufp[1*2 + w]  = wS;
    if (l == 7)  obufp[2*2 + w]  = wS;
    if (l == 15) obufp[3*2 + w]  = wS;
    if (l == 31) { obufp[4*2 + w] = wS; obufp[9*2 + w] = wV; }
    if (l == 62) obufp[0*2 + w]  = wV;
    if (l == 63) { obufp[10*2 + w] = wV; obufp[11*2 + w] = wV; }
    __syncthreads();

    if ((tid & 127) < NQ) {
        const int q = tid & 127;
        const float p0 = obufp[q*2 + 0], p1 = obufp[q*2 + 1];
        out[b * NQ + q] = (q == 0 || q == 11) ? (p0 - p1) : (p0 + p1);
    }
}

extern "C" void kernel_launch(void* const* d_in, const int* in_sizes, int n_in,
                              void* d_out, int out_size, void* d_ws, size_t ws_size,
                              hipStream_t stream) {
    const float* x  = (const float*)d_in[0];   // (1024, 12) f32
    const float* th = (const float*)d_in[1];   // (2, 12)    f32
    float* out = (float*)d_out;                // (1024, 12) f32
    (void)in_sizes; (void)n_in; (void)out_size; (void)d_ws; (void)ws_size;

    qc_kernel<<<BATCH / 4, 512, 0, stream>>>(x, th, out);   // 4 elems/block, 8 waves
}

// Round 4
// 9.644 us; speedup vs baseline: 1.1973x; 1.0040x over previous
//
#include <hip/hip_runtime.h>

#define NQ    12
#define BATCH 1024

typedef float v2 __attribute__((ext_vector_type(2)));
typedef float v4 __attribute__((ext_vector_type(4)));

// tangent-form packed RY on v2-index bit P: A' = [[1,-t],[t,1]] applied to (m, m|2^P)
template<int P>
__device__ __forceinline__ void ryp_t(v2 A[16], float t) {
#pragma unroll
    for (int m = 0; m < 16; ++m) {
        if ((m & (1 << P)) == 0) {
            const int j = m | (1 << P);
            const v2 Ai = A[m], Aj = A[j];
            A[m] = Ai - t * Aj;      // 1 pk_fma
            A[j] = Aj + t * Ai;      // 1 pk_fma
        }
    }
}

// tangent-form RY on the within-v2 bit: e' = e - t*o, o' = o + t*e (1 pk_fma via .yx)
__device__ __forceinline__ void ry0_t(v2 A[16], float t) {
    const v2 tv = v2{-t, t};
#pragma unroll
    for (int m = 0; m < 16; ++m) {
        const v2 sw = v2{A[m].y, A[m].x};
        A[m] = A[m] + tv * sw;
    }
}

__device__ __forceinline__ float rdlane(float v, int lane) {
    return __uint_as_float(__builtin_amdgcn_readlane(__float_as_uint(v), lane));
}

// DPP quad_perm cross-lane (VALU pipe): 0xB1 = xor1 [1,0,3,2], 0x4E = xor2 [2,3,0,1]
template<int CTRL>
__device__ __forceinline__ float dppx(float v) {
    return __int_as_float(__builtin_amdgcn_mov_dpp(__float_as_int(v), CTRL, 0xF, 0xF, true));
}
// ds_swizzle BitMode: offset = (xor<<10) | 0x1F  (xor within 32-lane group)
template<int PAT>
__device__ __forceinline__ float swz(float v) {
    return __int_as_float(__builtin_amdgcn_ds_swizzle(__float_as_int(v), PAT));
}

__global__ __launch_bounds__(512, 2)
void qc_kernel(const float* __restrict__ x, const float* __restrict__ th,
               float* __restrict__ out) {
    // 4 independent batch elements (wave-pairs) per block; per pair:
    // col-major transpose buffer: addr = w*2176 + col*68 + row  (stride 68 = 64+4 pad)
    __shared__ __attribute__((aligned(16))) float buf1[4 * 4352];
    __shared__ float obuf[4 * 24];

    const int tid = threadIdx.x;
    const int p = tid >> 7;               // wave-pair (batch sub-element) 0..3
    const int w = (tid >> 6) & 1;         // wave bit within pair = qubit 11
    const int l = tid & 63;
    const int b = blockIdx.x * 4 + p;
    const float* xb = x + b * NQ;
    float* bufp  = &buf1[p * 4352];
    float* obufp = &obuf[p * 24];

    // ---- lane-parallel sincos (verified R0) ----
    const int q_ = l & 31;
    float ang;
    if (l & 32) ang = (q_ < 12) ? 0.5f * th[NQ + q_] : 0.0f;
    else        { const int m_ = (q_ < 12) ? q_ : 11; ang = 0.5f * (xb[m_] + th[m_]); }
    float sv_, cv_;
    __sincosf(ang, &sv_, &cv_);
    const float tl = __fdividef(sv_, cv_);   // tan(ang); valid where used (lanes 32..43)

    // C = prod_{q=0..11} cos(th1_q/2): product tree over lanes 32..47 (DPP + swizzle)
    float pt = cv_;
    pt *= dppx<0xB1>(pt);        // xor 1
    pt *= dppx<0x4E>(pt);        // xor 2
    pt *= swz<0x101F>(pt);       // xor 4
    pt *= swz<0x201F>(pt);       // xor 8
    const float C = rdlane(pt, 32);

    float c_[NQ], s_[NQ], t1[NQ];
#pragma unroll
    for (int q = 0; q < NQ; ++q) {
        c_[q] = rdlane(cv_, q);
        s_[q] = rdlane(sv_, q);
        t1[q] = rdlane(tl, 32 + q);
    }

    // ---- build POST-ring#1 state, layout L1 (verified R0): ----
    // t0..t4 = reg bits (qubits 0..4), l0..l5 = lane bits (qubits 5..10), wave = qubit 11
    const int l0=l&1, l1=(l>>1)&1, l2=(l>>2)&1, l3=(l>>3)&1, l4=(l>>4)&1, l5=(l>>5)&1;
    float GL = ((l1^l0) ? s_[6] : c_[6]) * ((l2^l1) ? s_[7] : c_[7]);
    GL *= ((l3^l2) ? s_[8] : c_[8]) * ((l4^l3) ? s_[9] : c_[9]);
    GL *= ((l5^l4) ? s_[10] : c_[10]) * ((w^l5) ? s_[11] : c_[11]);
    GL *= C;                                        // deferred layer-1 cosine product
    const float GL0 = GL * (l0 ? s_[5] : c_[5]);    // regs with r4=0  (b5 = l0)
    const float GL1 = GL * (l0 ? c_[5] : s_[5]);    // regs with r4=1  (b5 = l0^1)

    const float f0_0 = w ? s_[0] : c_[0], f0_1 = w ? c_[0] : s_[0];   // g0(r0^w)
    const float f1_0 = w ? s_[1] : c_[1], f1_1 = w ? c_[1] : s_[1];   // g1(u^w)

    v2 A[16];
    A[0] = v2{f0_0 * f1_0, f0_1 * f1_1};
    A[1] = v2{f0_0 * f1_1, f0_1 * f1_0};
#pragma unroll
    for (int k = 2; k < 4; ++k) {
#pragma unroll
        for (int m = 0; m < (1 << (k - 1)); ++m) {
            const int bp = (m >> (k - 2)) & 1;
            A[m | (1 << (k - 1))] = A[m] * (bp ? c_[k] : s_[k]);
            A[m]                  = A[m] * (bp ? s_[k] : c_[k]);
        }
    }
    // k=4 step with GL0/GL1 merged into the coefficients (saves a 16-pk-mul pass)
    {
        const float cH = c_[4] * GL1, sH = s_[4] * GL1;
        const float cL = c_[4] * GL0, sL = s_[4] * GL0;
#pragma unroll
        for (int m = 0; m < 8; ++m) {
            const int bp = (m >> 2) & 1;
            A[m | 8] = A[m] * (bp ? cH : sH);
            A[m]     = A[m] * (bp ? sL : cL);
        }
    }

    // ---- layer-1 phase 1: qubits 0..4 on reg bits (tangent form) ----
    ry0_t(A, t1[0]);
    ryp_t<0>(A, t1[1]);
    ryp_t<1>(A, t1[2]);
    ryp_t<2>(A, t1[3]);
    ryp_t<3>(A, t1[4]);

    // ---- fold tangent-RY(q10) BEFORE transpose: q10 = lane bit 5 here ----
    // (commutes with RY(q11) and with the transpose; sign uses owner's l5)
    {
        const float s10 = l5 ? t1[10] : -t1[10];
#pragma unroll
        for (int m = 0; m < 16; ++m) {
            const v2 pr = v2{__shfl_xor(A[m].x, 32, 64), __shfl_xor(A[m].y, 32, 64)};
            A[m] = A[m] + s10 * pr;      // 1 pk_fma
        }
    }

    // ---- transpose write (col-major): col = 2m+c (qubits 0..4), row = l ----
    {
        float* wp = &bufp[w * 2176 + l];
#pragma unroll
        for (int m = 0; m < 16; ++m) {
            wp[(2*m)   * 68] = A[m].x;
            wp[(2*m+1) * 68] = A[m].y;
        }
    }
    __syncthreads();

    // ---- transpose read (16 x ds_read_b128, 2 streams) + fold tangent-RY(q11) ----
    // rows already q10-folded; own rows = row-bit5 == l5; partner stream = other wave
    {
        const float s11 = w ? t1[11] : -t1[11];
        const int basec = (l & 31) * 68 + (l & 32);
        const float* p0 = &bufp[ w      * 2176 + basec];   // own q11
        const float* p1 = &bufp[(w ^ 1) * 2176 + basec];   // flip q11 (partner wave)
#pragma unroll
        for (int k = 0; k < 8; ++k) {
            const v4 a  = *reinterpret_cast<const v4*>(p0 + 4*k);
            const v4 bq = *reinterpret_cast<const v4*>(p1 + 4*k);
            const v4 r = a + s11 * bq;
            A[2*k]   = v2{r.x, r.y};
            A[2*k+1] = v2{r.z, r.w};
        }
    }
    // layout L2: reg bits = qubits 5..9, lane bits 0-4 = qubits 0..4,
    //            lane bit 5 = qubit 10, wave = qubit 11 (q10 & q11 gates applied)

    // ---- layer-1 phase 2: qubits 5..9 on reg bits (tangent form) ----
    ry0_t(A, t1[5]);
    ryp_t<0>(A, t1[6]);
    ryp_t<1>(A, t1[7]);
    ryp_t<2>(A, t1[8]);
    ryp_t<3>(A, t1[9]);

    // ---- measurement: packed pairwise tree (ring #2 absorbed; L2 mapping) ----
    // S = sum; P1 sign t0; P3 sign t0^t1; P7 t0^t1^t2; PF t0..t3; PV t0..t4
#pragma unroll
    for (int m = 0; m < 16; ++m) A[m] *= A[m];

    v2 e[8], f[8];
#pragma unroll
    for (int i = 0; i < 8; ++i) { e[i] = A[2*i] + A[2*i+1]; f[i] = A[2*i] - A[2*i+1]; }
    v2 se = ((e[0]+e[1]) + (e[2]+e[3])) + ((e[4]+e[5]) + (e[6]+e[7]));
    v2 sf = ((f[0]+f[1]) + (f[2]+f[3])) + ((f[4]+f[5]) + (f[6]+f[7]));
    v2 gq[4];
#pragma unroll
    for (int j = 0; j < 4; ++j) gq[j] = f[2*j] - f[2*j+1];
    const v2 sg2 = (gq[0]+gq[1]) + (gq[2]+gq[3]);
    const v2 h0 = gq[0] - gq[1], h1 = gq[2] - gq[3];
    const v2 sh = h0 + h1;
    const v2 iv = h0 - h1;
    const float S  = se.x + se.y;
    const float P1 = se.x - se.y;
    const float P3 = sf.x - sf.y;
    const float P7 = sg2.x - sg2.y;
    const float PF = sh.x - sh.y;
    const float PV = iv.x - iv.y;

    // Z5..Z8: packed 4-value butterfly (lane-mask 0x1F sign applied first)
    const int pl5 = __popc(l & 31) & 1;
    float y0 = pl5 ? -P1 : P1;
    float y1 = pl5 ? -P3 : P3;
    float y2 = pl5 ? -P7 : P7;
    float y3 = pl5 ? -PF : PF;
    y0 += dppx<0xB1>(y0); y1 += dppx<0xB1>(y1);
    y2 += dppx<0xB1>(y2); y3 += dppx<0xB1>(y3);
    y0 += dppx<0x4E>(y0); y1 += dppx<0x4E>(y1);
    y2 += dppx<0x4E>(y2); y3 += dppx<0x4E>(y3);
    const int g = l & 3;
    float y = (g == 0) ? y0 : (g == 1) ? y1 : (g == 2) ? y2 : y3;
    y += swz<0x101F>(y);          // xor 4
    y += swz<0x201F>(y);          // xor 8
    y += swz<0x401F>(y);          // xor 16
    y += __shfl_xor(y, 32, 64);   // xor 32
    if (l < 4) obufp[(5 + l) * 2 + w] = y;   // lane l holds full sum of value l&3

    // WHT of S (Z1..Z4 at lanes 3,7,15,31) and PV (Z0@62, Z9@31, Z10/Z11@63)
    // fma form: w' = fma(sign_k, w, partner), sign_k = bit_k ? -1 : +1
    const float sg0 = (l & 1)  ? -1.f : 1.f;
    const float sg1 = (l & 2)  ? -1.f : 1.f;
    const float sg2s = (l & 4) ? -1.f : 1.f;
    const float sg3 = (l & 8)  ? -1.f : 1.f;
    const float sg4 = (l & 16) ? -1.f : 1.f;
    const float sg5 = (l & 32) ? -1.f : 1.f;
    float wS = S, wV = PV;
    { const float pS = dppx<0xB1>(wS),  pV = dppx<0xB1>(wV);  wS = __builtin_fmaf(sg0, wS, pS); wV = __builtin_fmaf(sg0, wV, pV); }
    { const float pS = dppx<0x4E>(wS),  pV = dppx<0x4E>(wV);  wS = __builtin_fmaf(sg1, wS, pS); wV = __builtin_fmaf(sg1, wV, pV); }
    { const float pS = swz<0x101F>(wS), pV = swz<0x101F>(wV); wS = __builtin_fmaf(sg2s, wS, pS); wV = __builtin_fmaf(sg2s, wV, pV); }
    { const float pS = swz<0x201F>(wS), pV = swz<0x201F>(wV); wS = __builtin_fmaf(sg3, wS, pS); wV = __builtin_fmaf(sg3, wV, pV); }
    { const float pS = swz<0x401F>(wS), pV = swz<0x401F>(wV); wS = __builtin_fmaf(sg4, wS, pS); wV = __builtin_fmaf(sg4, wV, pV); }
    { const float pS = __shfl_xor(wS, 32, 64), pV = __shfl_xor(wV, 32, 64);
      wS = __builtin_fmaf(sg5, wS, pS); wV = __builtin_fmaf(sg5, wV, pV); }

    if (l == 3)  obufp[1*2 + w]  = wS;
    if (l == 7)  obufp[2*2 + w]  = wS;
    if (l == 15) obufp[3*2 + w]  = wS;
    if (l == 31) { obufp[4*2 + w] = wS; obufp[9*2 + w] = wV; }
    if (l == 62) obufp[0*2 + w]  = wV;
    if (l == 63) { obufp[10*2 + w] = wV; obufp[11*2 + w] = wV; }
    __syncthreads();

    if ((tid & 127) < NQ) {
        const int q = tid & 127;
        const float p0 = obufp[q*2 + 0], p1 = obufp[q*2 + 1];
        out[b * NQ + q] = (q == 0 || q == 11) ? (p0 - p1) : (p0 + p1);
    }
}

extern "C" void kernel_launch(void* const* d_in, const int* in_sizes, int n_in,
                              void* d_out, int out_size, void* d_ws, size_t ws_size,
                              hipStream_t stream) {
    const float* x  = (const float*)d_in[0];   // (1024, 12) f32
    const float* th = (const float*)d_in[1];   // (2, 12)    f32
    float* out = (float*)d_out;                // (1024, 12) f32
    (void)in_sizes; (void)n_in; (void)out_size; (void)d_ws; (void)ws_size;

    qc_kernel<<<BATCH / 4, 512, 0, stream>>>(x, th, out);   // 4 elems/block, 8 waves
}